// Round 3
// baseline (143.729 us; speedup 1.0000x reference)
//
#include <hip/hip_runtime.h>

typedef __attribute__((ext_vector_type(8))) short bf16x8;
typedef __attribute__((ext_vector_type(4))) float f32x4;

#define HWSZ 65536

__device__ inline unsigned to_bf16u(float f) {
    union { float f; unsigned u; } c; c.f = f;
    unsigned u = c.u;
    return (u + 0x7fffu + ((u >> 16) & 1u)) >> 16;   // round-nearest-even
}

// Pre-kernel: wgt fp32 [co][ci][9] -> bf16 swizzled ws [chunk][kpos][co][4 slots][8]
__global__ void wcvt(const float* __restrict__ wgt, unsigned short* __restrict__ wsw) {
    int idx = blockIdx.x * 256 + threadIdx.x;       // 36864 total
    int co   = idx / 576;
    int rem  = idx - co * 576;
    int ci   = rem / 9;
    int kpos = rem - ci * 9;
    unsigned short v = (unsigned short)to_bf16u(wgt[idx]);
    int chunk = ci >> 5, cil = ci & 31;
    int slot = (cil >> 3) ^ ((co >> 1) & 3);
    wsw[((chunk * 9 + kpos) * 64 + co) * 32 + slot * 8 + (cil & 7)] = v;
}

__global__ __launch_bounds__(256, 2) void maskconv_mfma(
    const float* __restrict__ x, const int* __restrict__ mask,
    const unsigned short* __restrict__ wsw, const float* __restrict__ bias,
    float* __restrict__ out)
{
    __shared__ unsigned short xs[612 * 32];   // 39168 B: [pixel 18x34][ci32], swizzled
    __shared__ unsigned short wl[9 * 64 * 32];// 36864 B: [kpos][co][ci32], swizzled (1 chunk)

    const int tid  = threadIdx.x;
    const int lane = tid & 63;
    const int wv   = tid >> 6;          // wave 0..3
    const int l15  = lane & 15;
    const int l4   = lane >> 4;

    const int tileid = blockIdx.x;      // 128: 8 w-tiles x 16 h-tiles
    const int tw = (tileid & 7) * 32;
    const int th = (tileid >> 3) * 16;
    const int b  = blockIdx.y;

    const float* xb = x + (size_t)b * 64 * HWSZ;
    char* xsb = (char*)xs;
    char* wlb = (char*)wl;
    const int hl = wv * 4;              // wave's first local output row

    f32x4 acc[8][4];
    #pragma unroll
    for (int f = 0; f < 8; ++f)
        #pragma unroll
        for (int j = 0; j < 4; ++j)
            acc[f][j] = (f32x4){0.f, 0.f, 0.f, 0.f};

    // ---- precompute the 10 stage-pass offsets (shared by both chunks) ----
    int offv[10];
    unsigned vmask = 0;
    #pragma unroll
    for (int p = 0; p < 10; ++p) {
        int pi = p * 64 + lane;
        int r   = pi / 34;
        int lcv = pi - r * 34;
        int gr = th - 1 + r;
        int gc = tw - 1 + lcv;
        unsigned inb = (pi < 612) & ((unsigned)gr < 256u) & ((unsigned)gc < 256u);
        offv[p] = inb ? (gr * 256 + gc) : 0;
        vmask |= inb << p;
    }

    for (int c = 0; c < 2; ++c) {
        // ---- async weight stage: 9 x global_load_lds(16B) per thread ----
        #pragma unroll
        for (int i = 0; i < 9; ++i) {
            const unsigned short* g = wsw + c * 18432 + (i * 4 + wv) * 512 + lane * 8;
            unsigned short* l = wl + (i * 4 + wv) * 512;
            __builtin_amdgcn_global_load_lds(
                (const __attribute__((address_space(1))) void*)(const void*)g,
                (__attribute__((address_space(3))) void*)(void*)l, 16, 0, 0);
        }

        // ---- x stage: wave wv handles ci-octet wv; 1 pixel -> 1 b128 write ----
        {
            const float* srcc = xb + (size_t)(c * 32 + wv * 8) * HWSZ;
            #pragma unroll
            for (int p = 0; p < 10; ++p) {
                int pi = p * 64 + lane;
                if (p < 9 || lane < 36) {
                    int off = offv[p];
                    float v[8];
                    #pragma unroll
                    for (int k = 0; k < 8; ++k)
                        v[k] = srcc[(size_t)k * HWSZ + off];
                    if (!((vmask >> p) & 1u)) {
                        #pragma unroll
                        for (int k = 0; k < 8; ++k) v[k] = 0.f;
                    }
                    unsigned u[4];
                    #pragma unroll
                    for (int k = 0; k < 4; ++k)
                        u[k] = to_bf16u(v[2 * k]) | (to_bf16u(v[2 * k + 1]) << 16);
                    int r   = pi / 34;
                    int lcv = pi - r * 34;
                    int s   = (lcv >> 1) & 3;
                    *(uint4*)(xsb + pi * 64 + ((wv ^ s) << 4)) =
                        (uint4){u[0], u[1], u[2], u[3]};
                }
            }
        }
        __syncthreads();   // drains global_load_lds (vmcnt) + ds_writes (lgkm)

        // ---- MFMA: 9 kpos-steps, K=32 ----
        #pragma unroll
        for (int kh = 0; kh < 3; ++kh) {
            #pragma unroll
            for (int kw = 0; kw < 3; ++kw) {
                const int kpos = kh * 3 + kw;
                bf16x8 bfrag[4];
                #pragma unroll
                for (int j = 0; j < 4; ++j) {
                    int co = j * 16 + l15;
                    int slot = l4 ^ ((co >> 1) & 3);
                    bfrag[j] = *(const bf16x8*)(wlb + (kpos * 64 + co) * 64 + (slot << 4));
                }
                #pragma unroll
                for (int f = 0; f < 8; ++f) {
                    int lc = (f & 1) * 16 + l15 + kw;
                    int r  = hl + (f >> 1) + kh;
                    int s  = (lc >> 1) & 3;
                    bf16x8 afrag = *(const bf16x8*)(xsb + (r * 34 + lc) * 64 + ((l4 ^ s) << 4));
                    #pragma unroll
                    for (int j = 0; j < 4; ++j)
                        acc[f][j] = __builtin_amdgcn_mfma_f32_16x16x32_bf16(
                            afrag, bfrag[j], acc[f][j], 0, 0, 0);
                }
            }
        }
        if (c == 0) __syncthreads();   // xs/wl reused by chunk 1
    }

    // ---- epilogue: bias (fp32) + mask, float4 stores ----
    const int* mb = mask + (size_t)b * HWSZ;
    float bv[4];
    #pragma unroll
    for (int j = 0; j < 4; ++j) bv[j] = bias[j * 16 + l15];

    #pragma unroll
    for (int f = 0; f < 8; ++f) {
        int h  = th + hl + (f >> 1);
        int wq = tw + (f & 1) * 16 + l4 * 4;
        int4 mv = *(const int4*)(mb + h * 256 + wq);
        float m0 = (float)mv.x, m1 = (float)mv.y, m2 = (float)mv.z, m3 = (float)mv.w;
        #pragma unroll
        for (int j = 0; j < 4; ++j) {
            int co = j * 16 + l15;
            float4 o;
            o.x = (acc[f][j].x + bv[j]) * m0;
            o.y = (acc[f][j].y + bv[j]) * m1;
            o.z = (acc[f][j].z + bv[j]) * m2;
            o.w = (acc[f][j].w + bv[j]) * m3;
            *(float4*)(out + (((size_t)(b * 64 + co)) << 16) + h * 256 + wq) = o;
        }
    }
}

extern "C" void kernel_launch(void* const* d_in, const int* in_sizes, int n_in,
                              void* d_out, int out_size, void* d_ws, size_t ws_size,
                              hipStream_t stream) {
    const float* x    = (const float*)d_in[0];
    const int*   mask = (const int*)d_in[1];
    const float* wgt  = (const float*)d_in[2];
    const float* bias = (const float*)d_in[3];
    float* out = (float*)d_out;
    unsigned short* wsw = (unsigned short*)d_ws;    // 73728 B used

    wcvt<<<dim3(144), dim3(256), 0, stream>>>(wgt, wsw);
    maskconv_mfma<<<dim3(128, 8), dim3(256), 0, stream>>>(x, mask, wsw, bias, out);
}